// Round 1
// baseline (1979.878 us; speedup 1.0000x reference)
//
#include <hip/hip_runtime.h>
#include <math.h>

constexpr int NN = 4;    // batch
constexpr int CC = 128;  // channels

// ---------------- generic 3x3 conv, pad=1, OCB output channels / thread ----
// act: 0 = none, 1 = relu, 2 = 2*sigmoid ; bn applied if bg != nullptr
template<int OCB>
__global__ __launch_bounds__(256)
void conv3x3_k(const float* __restrict__ in, const float* __restrict__ w,
               const float* __restrict__ bias,
               const float* __restrict__ bg, const float* __restrict__ bb,
               const float* __restrict__ bm, const float* __restrict__ bv,
               float* __restrict__ out,
               int Cin, int Cout, int H, int W, int act)
{
    const int HW = H * W;
    int p = blockIdx.x * 256 + threadIdx.x;
    if (p >= NN * HW) return;
    int n = p / HW, r = p - n * HW;
    int y = r / W, x = r - y * W;
    int oc0 = blockIdx.y * OCB;

    float acc[OCB];
#pragma unroll
    for (int j = 0; j < OCB; ++j) {
        int oc = oc0 + j;
        acc[j] = bias[oc < Cout ? oc : 0];
    }

    const float* inb = in + (size_t)n * Cin * HW;
    for (int c = 0; c < Cin; ++c) {
        const float* ic = inb + (size_t)c * HW;
        float v[9];
#pragma unroll
        for (int ky = 0; ky < 3; ++ky) {
            int yy = y + ky - 1;
            bool yv = (yy >= 0) && (yy < H);
#pragma unroll
            for (int kx = 0; kx < 3; ++kx) {
                int xx = x + kx - 1;
                bool ok = yv && (xx >= 0) && (xx < W);
                v[ky * 3 + kx] = ok ? ic[yy * W + xx] : 0.f;
            }
        }
#pragma unroll
        for (int j = 0; j < OCB; ++j) {
            int oc = oc0 + j; if (oc >= Cout) oc = Cout - 1;
            const float* wr = w + ((size_t)oc * Cin + c) * 9;
#pragma unroll
            for (int t = 0; t < 9; ++t) acc[j] += v[t] * wr[t];
        }
    }

#pragma unroll
    for (int j = 0; j < OCB; ++j) {
        int oc = oc0 + j;
        if (oc >= Cout) continue;
        float val = acc[j];
        if (bg) {
            float sc = bg[oc] * rsqrtf(bv[oc] + 1e-5f);
            val = val * sc + (bb[oc] - bm[oc] * sc);
        }
        if (act == 1) val = fmaxf(val, 0.f);
        else if (act == 2) val = 2.f / (1.f + expf(-val));
        out[((size_t)n * Cout + oc) * HW + r] = val;
    }
}

// ------------- deformable sampling for one kernel tap k --------------------
// s[n][c][p] = bilinear(h[n][c]; py,px) * mask, zero outside
__global__ __launch_bounds__(256)
void dsample_k(const float* __restrict__ h, const float* __restrict__ off,
               const float* __restrict__ msk, float* __restrict__ s,
               int H, int W, int k)
{
    const int HW = H * W;
    const int NCB = CC / 16;                   // 8 channel-blocks of 16
    int idx = blockIdx.x * 256 + threadIdx.x;
    if (idx >= NN * NCB * HW) return;
    int p = idx % HW;
    int t = idx / HW;
    int cb = t % NCB, n = t / NCB;
    int y = p / W, x = p - y * W;

    float dy = off[((size_t)n * 18 + 2 * k) * HW + p];
    float dx = off[((size_t)n * 18 + 2 * k + 1) * HW + p];
    float m  = msk[((size_t)n * 9 + k) * HW + p];

    float py = (float)y - 1.f + (float)(k / 3) + dy;
    float px = (float)x - 1.f + (float)(k % 3) + dx;
    float fy = floorf(py), fx = floorf(px);
    int y0 = (int)fy, x0 = (int)fx;
    float wy = py - fy, wx = px - fx;

    bool y0v = (y0 >= 0) && (y0 < H);
    bool y1v = (y0 + 1 >= 0) && (y0 + 1 < H);
    bool x0v = (x0 >= 0) && (x0 < W);
    bool x1v = (x0 + 1 >= 0) && (x0 + 1 < W);
    int yc0 = min(max(y0, 0), H - 1);
    int yc1 = min(max(y0 + 1, 0), H - 1);
    int xc0 = min(max(x0, 0), W - 1);
    int xc1 = min(max(x0 + 1, 0), W - 1);

    float w00 = (1.f - wy) * (1.f - wx) * ((y0v && x0v) ? m : 0.f);
    float w01 = (1.f - wy) * wx         * ((y0v && x1v) ? m : 0.f);
    float w10 = wy * (1.f - wx)         * ((y1v && x0v) ? m : 0.f);
    float w11 = wy * wx                 * ((y1v && x1v) ? m : 0.f);

    int i00 = yc0 * W + xc0, i01 = yc0 * W + xc1;
    int i10 = yc1 * W + xc0, i11 = yc1 * W + xc1;

    const float* hb = h + (size_t)(n * CC + cb * 16) * HW;
    float* sb = s + (size_t)(n * CC + cb * 16) * HW + p;
#pragma unroll
    for (int cc = 0; cc < 16; ++cc) {
        const float* hc = hb + (size_t)cc * HW;
        float val = w00 * hc[i00] + w01 * hc[i01] + w10 * hc[i10] + w11 * hc[i11];
        sb[(size_t)cc * HW] = val;
    }
}

// ------------- 1x1-GEMM accumulate: out (+)= s * w_def[:,:,k] --------------
template<int OCB>
__global__ __launch_bounds__(256)
void gemm1x1_acc(const float* __restrict__ s, const float* __restrict__ w,
                 const float* __restrict__ bias, float* __restrict__ out,
                 int H, int W, int k, int init)
{
    const int HW = H * W;
    int p = blockIdx.x * 256 + threadIdx.x;
    if (p >= NN * HW) return;
    int n = p / HW, r = p - n * HW;
    int oc0 = blockIdx.y * OCB;

    float acc[OCB];
#pragma unroll
    for (int j = 0; j < OCB; ++j) acc[j] = init ? bias[oc0 + j] : 0.f;

    const float* sb = s + (size_t)n * CC * HW + r;
    for (int c = 0; c < CC; ++c) {
        float v = sb[(size_t)c * HW];
#pragma unroll
        for (int j = 0; j < OCB; ++j)
            acc[j] += v * w[((size_t)(oc0 + j) * CC + c) * 9 + k];
    }
#pragma unroll
    for (int j = 0; j < OCB; ++j) {
        float* o = out + ((size_t)n * CC + oc0 + j) * HW + r;
        *o = init ? acc[j] : (*o + acc[j]);
    }
}

// ------------- residual fuse: T = relu(bn2(T) + bn3(x*wds + bds)) ----------
template<int OCB>
__global__ __launch_bounds__(256)
void resfuse_k(const float* __restrict__ x, const float* __restrict__ wds,
               const float* __restrict__ bds,
               const float* __restrict__ g2, const float* __restrict__ be2,
               const float* __restrict__ m2, const float* __restrict__ v2,
               const float* __restrict__ g3, const float* __restrict__ be3,
               const float* __restrict__ m3, const float* __restrict__ v3,
               float* __restrict__ T, int H, int W)
{
    const int HW = H * W;
    int p = blockIdx.x * 256 + threadIdx.x;
    if (p >= NN * HW) return;
    int n = p / HW, r = p - n * HW;
    int oc0 = blockIdx.y * OCB;

    float acc[OCB];
#pragma unroll
    for (int j = 0; j < OCB; ++j) acc[j] = bds[oc0 + j];

    const float* xb = x + (size_t)n * CC * HW + r;
    for (int c = 0; c < CC; ++c) {
        float v = xb[(size_t)c * HW];
#pragma unroll
        for (int j = 0; j < OCB; ++j)
            acc[j] += v * wds[(size_t)(oc0 + j) * CC + c];
    }
#pragma unroll
    for (int j = 0; j < OCB; ++j) {
        int oc = oc0 + j;
        float sc3 = g3[oc] * rsqrtf(v3[oc] + 1e-5f);
        float res = acc[j] * sc3 + (be3[oc] - m3[oc] * sc3);
        float sc2 = g2[oc] * rsqrtf(v2[oc] + 1e-5f);
        size_t idx = ((size_t)n * CC + oc) * HW + r;
        float d = T[idx] * sc2 + (be2[oc] - m2[oc] * sc2);
        T[idx] = fmaxf(d + res, 0.f);
    }
}

// ------------- maxpool 2x2, stride 1, pad (1,1) -> (H+1, W+1) --------------
__global__ __launch_bounds__(256)
void maxpool_k(const float* __restrict__ in, float* __restrict__ out, int H, int W)
{
    int Ho = H + 1, Wo = W + 1;
    int tot = NN * CC * Ho * Wo;
    int idx = blockIdx.x * 256 + threadIdx.x;
    if (idx >= tot) return;
    int ox = idx % Wo; int t = idx / Wo;
    int oy = t % Ho;   t /= Ho;
    int c = t % CC;    int n = t / CC;
    const float* ib = in + ((size_t)n * CC + c) * H * W;
    float mx = -INFINITY;
#pragma unroll
    for (int d = 0; d < 2; ++d) {
        int iy = oy - 1 + d;
        if (iy < 0 || iy >= H) continue;
#pragma unroll
        for (int e = 0; e < 2; ++e) {
            int ix = ox - 1 + e;
            if (ix < 0 || ix >= W) continue;
            mx = fmaxf(mx, ib[iy * W + ix]);
        }
    }
    out[(((size_t)n * CC + c) * Ho + oy) * Wo + ox] = mx;
}

extern "C" void kernel_launch(void* const* d_in, const int* in_sizes, int n_in,
                              void* d_out, int out_size, void* d_ws, size_t ws_size,
                              hipStream_t stream)
{
    const float* x0    = (const float*)d_in[0];
    const float* w1    = (const float*)d_in[1];
    const float* b1    = (const float*)d_in[2];
    const float* g1    = (const float*)d_in[3];
    const float* be1   = (const float*)d_in[4];
    const float* m1    = (const float*)d_in[5];
    const float* v1    = (const float*)d_in[6];
    const float* w_off = (const float*)d_in[7];
    const float* b_off = (const float*)d_in[8];
    const float* w_mod = (const float*)d_in[9];
    const float* b_mod = (const float*)d_in[10];
    const float* w_def = (const float*)d_in[11];
    const float* b_def = (const float*)d_in[12];
    const float* g2    = (const float*)d_in[13];
    const float* be2   = (const float*)d_in[14];
    const float* m2    = (const float*)d_in[15];
    const float* v2    = (const float*)d_in[16];
    const float* w_ds  = (const float*)d_in[17];
    const float* b_ds  = (const float*)d_in[18];
    const float* g3    = (const float*)d_in[19];
    const float* be3   = (const float*)d_in[20];
    const float* m3    = (const float*)d_in[21];
    const float* v3    = (const float*)d_in[22];

    float* ws = (float*)d_ws;
    const size_t PLANE = (size_t)NN * CC * 65 * 65;  // max intermediate (block-1) plane
    float* Xb  = ws;                                 // block-0 pooled output (65x65)
    float* Hb  = Xb + PLANE;
    float* Tb  = Hb + PLANE;
    float* Sb  = Tb + PLANE;
    float* OFF = Sb + PLANE;
    float* MSK = OFF + (size_t)NN * 18 * 65 * 65;

    const float* cur = x0;
    for (int i = 0; i < 2; ++i) {
        int H = 64 + i, W = 64 + i;
        int HW = H * W, NP = NN * HW;
        int gx = (NP + 255) / 256;
        dim3 blk(256);

        const float* w1i   = w1    + (size_t)i * CC * CC * 9;
        const float* b1i   = b1    + (size_t)i * CC;
        const float* g1i   = g1  + i * CC, *be1i = be1 + i * CC, *m1i = m1 + i * CC, *v1i = v1 + i * CC;
        const float* woffi = w_off + (size_t)i * 18 * CC * 9;
        const float* boffi = b_off + (size_t)i * 18;
        const float* wmodi = w_mod + (size_t)i * 9 * CC * 9;
        const float* bmodi = b_mod + (size_t)i * 9;
        const float* wdefi = w_def + (size_t)i * CC * CC * 9;
        const float* bdefi = b_def + (size_t)i * CC;
        const float* g2i   = g2  + i * CC, *be2i = be2 + i * CC, *m2i = m2 + i * CC, *v2i = v2 + i * CC;
        const float* wdsi  = w_ds  + (size_t)i * CC * CC;
        const float* bdsi  = b_ds  + (size_t)i * CC;
        const float* g3i   = g3  + i * CC, *be3i = be3 + i * CC, *m3i = m3 + i * CC, *v3i = v3 + i * CC;

        // h = relu(bn1(conv3x3(x)))
        conv3x3_k<8><<<dim3(gx, 16), blk, 0, stream>>>(cur, w1i, b1i,
            g1i, be1i, m1i, v1i, Hb, CC, CC, H, W, 1);
        // off (18 ch), msk (9 ch, 2*sigmoid)
        conv3x3_k<8><<<dim3(gx, 3), blk, 0, stream>>>(Hb, woffi, boffi,
            nullptr, nullptr, nullptr, nullptr, OFF, CC, 18, H, W, 0);
        conv3x3_k<8><<<dim3(gx, 2), blk, 0, stream>>>(Hb, wmodi, bmodi,
            nullptr, nullptr, nullptr, nullptr, MSK, CC, 9, H, W, 2);
        // deformable conv: 9 x (sample + 1x1-GEMM accumulate) into Tb (raw)
        for (int k = 0; k < 9; ++k) {
            int nt = NN * (CC / 16) * HW;
            dsample_k<<<(nt + 255) / 256, blk, 0, stream>>>(Hb, OFF, MSK, Sb, H, W, k);
            gemm1x1_acc<8><<<dim3(gx, 16), blk, 0, stream>>>(Sb, wdefi, bdefi, Tb,
                H, W, k, k == 0);
        }
        // T = relu(bn2(T) + bn3(conv1x1(x)))
        resfuse_k<8><<<dim3(gx, 16), blk, 0, stream>>>(cur, wdsi, bdsi,
            g2i, be2i, m2i, v2i, g3i, be3i, m3i, v3i, Tb, H, W);
        // maxpool -> next input (or final output)
        int Ho = H + 1, Wo = W + 1;
        int tot = NN * CC * Ho * Wo;
        float* dst = (i == 0) ? Xb : (float*)d_out;
        maxpool_k<<<(tot + 255) / 256, blk, 0, stream>>>(Tb, dst, H, W);
        cur = Xb;
    }
}

// Round 2
// 363.576 us; speedup vs baseline: 5.4456x; 5.4456x over previous
//
#include <hip/hip_runtime.h>
#include <math.h>

constexpr int NN = 4;    // batch
constexpr int CC = 128;  // channels

typedef unsigned short u16;
typedef short bfrag __attribute__((ext_vector_type(8)));   // 8 bf16 (4 VGPR)
typedef float facc  __attribute__((ext_vector_type(4)));   // 4 f32 acc

__device__ inline float bf2f(u16 v) {
    unsigned u = ((unsigned)v) << 16; float f; __builtin_memcpy(&f, &u, 4); return f;
}
__device__ inline u16 f2bf(float f) {
    unsigned u; __builtin_memcpy(&u, &f, 4);
    unsigned r = u + 0x7FFFu + ((u >> 16) & 1u);
    return (u16)(r >> 16);
}

// =====================================================================
// 3x3 conv as MFMA GEMM over padded NHWC bf16 input.
// A: [NN][Hp][Wp][128] bf16, zero halo. B: [Cout][1152] bf16 (k = tap*128+c).
// MODE 0: +bias, bn, relu -> bf16 padded NHWC out (same Hp/Wp)
// MODE 1: +bias raw f32 -> Out[pix*32 + oc]
// =====================================================================
template<int WM, int WN, int MR, int NR, int MODE>
__global__ __launch_bounds__(WM*WN*64)
void conv3x3_mfma(const u16* __restrict__ A, const u16* __restrict__ B,
                  const float* __restrict__ bias,
                  const float* __restrict__ bg, const float* __restrict__ bb,
                  const float* __restrict__ bm, const float* __restrict__ bv,
                  void* __restrict__ Out, int H, int W)
{
    const int Hp = H + 2, Wp = W + 2, HW = H * W, NHW = NN * HW;
    const int lane = threadIdx.x & 63, wv = threadIdx.x >> 6;
    const int wn = wv % WN, wm = wv / WN;
    const int colc = lane & 15, kg = lane >> 4;
    const int m_base = blockIdx.x * (WM * MR * 16) + wm * (MR * 16);
    const int oc_base = wn * (NR * 16);

    size_t aoff[MR];
#pragma unroll
    for (int r = 0; r < MR; ++r) {
        int pix = m_base + r * 16 + colc; if (pix > NHW - 1) pix = NHW - 1;
        int n = pix / HW, rr = pix - n * HW;
        int y = rr / W, x = rr - y * W;
        aoff[r] = ((size_t)(n * Hp + y) * Wp + x) * 128 + kg * 8;
    }
    const u16* Brow[NR];
#pragma unroll
    for (int q = 0; q < NR; ++q)
        Brow[q] = B + (size_t)(oc_base + q * 16 + colc) * 1152 + kg * 8;

    facc acc[MR][NR];
#pragma unroll
    for (int r = 0; r < MR; ++r)
#pragma unroll
        for (int q = 0; q < NR; ++q) acc[r][q] = (facc){0.f, 0.f, 0.f, 0.f};

    for (int tap = 0; tap < 9; ++tap) {
        int ty = tap / 3, tx = tap - ty * 3;
        size_t toff = (size_t)(ty * Wp + tx) * 128;
#pragma unroll
        for (int cc = 0; cc < 4; ++cc) {
            bfrag a[MR], b[NR];
#pragma unroll
            for (int r = 0; r < MR; ++r)
                a[r] = *(const bfrag*)(A + aoff[r] + toff + cc * 32);
#pragma unroll
            for (int q = 0; q < NR; ++q)
                b[q] = *(const bfrag*)(Brow[q] + tap * 128 + cc * 32);
#pragma unroll
            for (int r = 0; r < MR; ++r)
#pragma unroll
                for (int q = 0; q < NR; ++q)
                    acc[r][q] = __builtin_amdgcn_mfma_f32_16x16x32_bf16(a[r], b[q], acc[r][q], 0, 0, 0);
        }
    }

#pragma unroll
    for (int r = 0; r < MR; ++r) {
#pragma unroll
        for (int j = 0; j < 4; ++j) {
            int pix = m_base + r * 16 + kg * 4 + j;
            if (pix >= NHW) continue;
            int n = pix / HW, rr = pix - n * HW;
            int y = rr / W, x = rr - y * W;
#pragma unroll
            for (int q = 0; q < NR; ++q) {
                int oc = oc_base + q * 16 + colc;
                float val = acc[r][q][j] + bias[oc];
                if constexpr (MODE == 0) {
                    float sc = bg[oc] * rsqrtf(bv[oc] + 1e-5f);
                    val = val * sc + (bb[oc] - bm[oc] * sc);
                    val = fmaxf(val, 0.f);
                    ((u16*)Out)[((size_t)(n * Hp + y + 1) * Wp + (x + 1)) * 128 + oc] = f2bf(val);
                } else {
                    ((float*)Out)[(size_t)pix * 32 + oc] = val;
                }
            }
        }
    }
}

// =====================================================================
// 1x1-style MFMA GEMM, K = NT*128.
// APAD: A is padded NHWC bf16 (addr via n,y,x); else A = [kt][NHW][128] bf16.
// MODE 0: tap-accumulate into T f32 [pix*128+oc] (init with bias when t0==0)
// MODE 1: residual fuse: T = relu( bn2(T) + bn3(D + bias) )
// =====================================================================
template<int NT, int MODE, bool APAD>
__global__ __launch_bounds__(256)
void gemm1x1_mfma(const u16* __restrict__ A, const u16* __restrict__ B, int ldb, int t0,
                  const float* __restrict__ bias,
                  const float* __restrict__ g2, const float* __restrict__ be2,
                  const float* __restrict__ m2, const float* __restrict__ v2,
                  const float* __restrict__ g3, const float* __restrict__ be3,
                  const float* __restrict__ m3, const float* __restrict__ v3,
                  float* __restrict__ T, int H, int W)
{
    const int Hp = H + 2, Wp = W + 2, HW = H * W, NHW = NN * HW;
    const int lane = threadIdx.x & 63, wv = threadIdx.x >> 6;  // WM=1, WN=4
    const int colc = lane & 15, kg = lane >> 4;
    const int m_base = blockIdx.x * 32;
    const int oc_base = wv * 32;
    constexpr int MR = 2, NR = 2;

    size_t aoff[MR];
#pragma unroll
    for (int r = 0; r < MR; ++r) {
        int pix = m_base + r * 16 + colc; if (pix > NHW - 1) pix = NHW - 1;
        if (APAD) {
            int n = pix / HW, rr = pix - n * HW;
            int y = rr / W, x = rr - y * W;
            aoff[r] = ((size_t)(n * Hp + y + 1) * Wp + (x + 1)) * 128 + kg * 8;
        } else {
            aoff[r] = (size_t)pix * 128 + kg * 8;
        }
    }
    const u16* Brow[NR];
#pragma unroll
    for (int q = 0; q < NR; ++q)
        Brow[q] = B + (size_t)(oc_base + q * 16 + colc) * ldb + kg * 8;

    facc acc[MR][NR];
#pragma unroll
    for (int r = 0; r < MR; ++r)
#pragma unroll
        for (int q = 0; q < NR; ++q) acc[r][q] = (facc){0.f, 0.f, 0.f, 0.f};

#pragma unroll
    for (int kt = 0; kt < NT; ++kt) {
        size_t abase = (size_t)kt * NHW * 128;
#pragma unroll
        for (int cc = 0; cc < 4; ++cc) {
            bfrag a[MR], b[NR];
#pragma unroll
            for (int r = 0; r < MR; ++r)
                a[r] = *(const bfrag*)(A + (APAD ? aoff[r] : aoff[r] + abase) + cc * 32);
#pragma unroll
            for (int q = 0; q < NR; ++q)
                b[q] = *(const bfrag*)(Brow[q] + kt * 128 + cc * 32);
#pragma unroll
            for (int r = 0; r < MR; ++r)
#pragma unroll
                for (int q = 0; q < NR; ++q)
                    acc[r][q] = __builtin_amdgcn_mfma_f32_16x16x32_bf16(a[r], b[q], acc[r][q], 0, 0, 0);
        }
    }

#pragma unroll
    for (int r = 0; r < MR; ++r) {
#pragma unroll
        for (int j = 0; j < 4; ++j) {
            int pix = m_base + r * 16 + kg * 4 + j;
            if (pix >= NHW) continue;
#pragma unroll
            for (int q = 0; q < NR; ++q) {
                int oc = oc_base + q * 16 + colc;
                size_t idx = (size_t)pix * 128 + oc;
                float val = acc[r][q][j];
                if constexpr (MODE == 0) {
                    if (t0 == 0) T[idx] = val + bias[oc];
                    else         T[idx] += val;
                } else {
                    val += bias[oc];
                    float sc3 = g3[oc] * rsqrtf(v3[oc] + 1e-5f);
                    float res = val * sc3 + (be3[oc] - m3[oc] * sc3);
                    float sc2 = g2[oc] * rsqrtf(v2[oc] + 1e-5f);
                    float d = T[idx] * sc2 + (be2[oc] - m2[oc] * sc2);
                    T[idx] = fmaxf(d + res, 0.f);
                }
            }
        }
    }
}

// =====================================================================
// Deformable bilinear sampling for 3 consecutive taps.
// Reads padded NHWC bf16 h and OFFMSK f32 [pix][32] (0..17 off, 18..26 raw msk).
// Writes S[kt][NHW][128] bf16, mask (2*sigmoid) applied.
// =====================================================================
__global__ __launch_bounds__(256)
void dsample3_k(const u16* __restrict__ Hb, const float* __restrict__ OM,
                u16* __restrict__ S, int H, int W, int k0)
{
    const int HW = H * W, NHW = NN * HW, Hp = H + 2, Wp = W + 2;
    int idx = blockIdx.x * 256 + threadIdx.x;
    if (idx >= 3 * NHW * 16) return;
    int cg = idx & 15; int t = idx >> 4;
    int p = t % NHW; int kt = t / NHW;
    int k = k0 + kt;
    int n = p / HW, rr = p - n * HW, y = rr / W, x = rr - y * W;

    float dy = OM[(size_t)p * 32 + 2 * k];
    float dx = OM[(size_t)p * 32 + 2 * k + 1];
    float mr = OM[(size_t)p * 32 + 18 + k];
    float m = 2.f / (1.f + expf(-mr));

    float py = (float)y - 1.f + (float)(k / 3) + dy;
    float px = (float)x - 1.f + (float)(k % 3) + dx;
    float fy = floorf(py), fx = floorf(px);
    int y0 = (int)fy, x0 = (int)fx;
    float wy = py - fy, wx = px - fx;

    bool y0v = (y0 >= 0) && (y0 < H), y1v = (y0 + 1 >= 0) && (y0 + 1 < H);
    bool x0v = (x0 >= 0) && (x0 < W), x1v = (x0 + 1 >= 0) && (x0 + 1 < W);
    int yc0 = min(max(y0, 0), H - 1), yc1 = min(max(y0 + 1, 0), H - 1);
    int xc0 = min(max(x0, 0), W - 1), xc1 = min(max(x0 + 1, 0), W - 1);

    float w00 = (1.f - wy) * (1.f - wx) * ((y0v && x0v) ? m : 0.f);
    float w01 = (1.f - wy) * wx         * ((y0v && x1v) ? m : 0.f);
    float w10 = wy * (1.f - wx)         * ((y1v && x0v) ? m : 0.f);
    float w11 = wy * wx                 * ((y1v && x1v) ? m : 0.f);

    const u16* hb = Hb + (size_t)n * Hp * Wp * 128 + cg * 8;
    const bfrag c00 = *(const bfrag*)(hb + ((size_t)(yc0 + 1) * Wp + (xc0 + 1)) * 128);
    const bfrag c01 = *(const bfrag*)(hb + ((size_t)(yc0 + 1) * Wp + (xc1 + 1)) * 128);
    const bfrag c10 = *(const bfrag*)(hb + ((size_t)(yc1 + 1) * Wp + (xc0 + 1)) * 128);
    const bfrag c11 = *(const bfrag*)(hb + ((size_t)(yc1 + 1) * Wp + (xc1 + 1)) * 128);

    bfrag o;
#pragma unroll
    for (int j = 0; j < 8; ++j) {
        float f = w00 * bf2f((u16)c00[j]) + w01 * bf2f((u16)c01[j])
                + w10 * bf2f((u16)c10[j]) + w11 * bf2f((u16)c11[j]);
        o[j] = (short)f2bf(f);
    }
    *(bfrag*)(S + ((size_t)kt * NHW + p) * 128 + cg * 8) = o;
}

// =====================================================================
// maxpool 2x2 stride1 pad1: H x W -> (H+1) x (W+1); input T f32 [pix][128]
// OUTMODE 0: to padded NHWC bf16 (next block input); 1: to NCHW f32 d_out
// =====================================================================
template<int OUTMODE>
__global__ __launch_bounds__(256)
void pool_k(const float* __restrict__ T, void* __restrict__ Out, int H, int W)
{
    const int HW = H * W, Ho = H + 1, Wo = W + 1;
    int tot = NN * Ho * Wo * 16;
    int idx = blockIdx.x * 256 + threadIdx.x;
    if (idx >= tot) return;
    int cg = idx & 15; int t = idx >> 4;
    int ox = t % Wo; t /= Wo; int oy = t % Ho; int n = t / Ho;

    float mx[8];
#pragma unroll
    for (int j = 0; j < 8; ++j) mx[j] = -INFINITY;
#pragma unroll
    for (int d = 0; d < 2; ++d) {
        int iy = oy - 1 + d;
        if (iy < 0 || iy >= H) continue;
#pragma unroll
        for (int e = 0; e < 2; ++e) {
            int ix = ox - 1 + e;
            if (ix < 0 || ix >= W) continue;
            const float* src = T + ((size_t)(n * HW + iy * W + ix)) * 128 + cg * 8;
#pragma unroll
            for (int j = 0; j < 8; ++j) mx[j] = fmaxf(mx[j], src[j]);
        }
    }
    if constexpr (OUTMODE == 0) {
        int Hp2 = Ho + 2, Wp2 = Wo + 2;
        bfrag o;
#pragma unroll
        for (int j = 0; j < 8; ++j) o[j] = (short)f2bf(mx[j]);
        *(bfrag*)((u16*)Out + ((size_t)(n * Hp2 + oy + 1) * Wp2 + (ox + 1)) * 128 + cg * 8) = o;
    } else {
#pragma unroll
        for (int j = 0; j < 8; ++j) {
            int c = cg * 8 + j;
            ((float*)Out)[(((size_t)n * 128 + c) * Ho + oy) * Wo + ox] = mx[j];
        }
    }
}

// ---- x (NCHW f32) -> padded NHWC bf16 (H=W=64, Hp=66) ----------------
__global__ __launch_bounds__(256)
void x0_to_nhwc(const float* __restrict__ x0, u16* __restrict__ Xp)
{
    int idx = blockIdx.x * 256 + threadIdx.x;
    if (idx >= NN * 64 * 64 * 16) return;
    int cg = idx & 15; int t = idx >> 4;
    int x = t & 63; t >>= 6; int y = t & 63; int n = t >> 6;
    bfrag o;
#pragma unroll
    for (int j = 0; j < 8; ++j) {
        int c = cg * 8 + j;
        o[j] = (short)f2bf(x0[(((size_t)n * 128 + c) * 64 + y) * 64 + x]);
    }
    *(bfrag*)(Xp + ((size_t)(n * 66 + y + 1) * 66 + (x + 1)) * 128 + cg * 8) = o;
}

// ---- weight repack to bf16 [oc][tap*128+c] layouts -------------------
__global__ __launch_bounds__(256)
void wconv_k(const float* __restrict__ w1, const float* __restrict__ woff,
             const float* __restrict__ wmod, const float* __restrict__ wdef,
             const float* __restrict__ wds,
             const float* __restrict__ boff, const float* __restrict__ bmod,
             u16* __restrict__ Wb1, u16* __restrict__ Wbom,
             u16* __restrict__ Wbdef, u16* __restrict__ Wbds,
             float* __restrict__ biasOM)
{
    int idx = blockIdx.x * 256 + threadIdx.x;
    const int N1 = 128 * 1152;
    if (idx < N1) {
        int oc = idx / 1152, k = idx % 1152, tap = k / 128, c = k % 128;
        Wb1[idx]   = f2bf(w1[((size_t)oc * 128 + c) * 9 + tap]);
        Wbdef[idx] = f2bf(wdef[((size_t)oc * 128 + c) * 9 + tap]);
        return;
    }
    idx -= N1;
    const int N2 = 32 * 1152;
    if (idx < N2) {
        int oc = idx / 1152, k = idx % 1152, tap = k / 128, c = k % 128;
        float v = 0.f;
        if (oc < 18)      v = woff[((size_t)oc * 128 + c) * 9 + tap];
        else if (oc < 27) v = wmod[((size_t)(oc - 18) * 128 + c) * 9 + tap];
        Wbom[idx] = f2bf(v);
        return;
    }
    idx -= N2;
    if (idx < 128 * 128) { Wbds[idx] = f2bf(wds[idx]); return; }
    idx -= 128 * 128;
    if (idx < 32) {
        biasOM[idx] = idx < 18 ? boff[idx] : (idx < 27 ? bmod[idx - 18] : 0.f);
    }
}

extern "C" void kernel_launch(void* const* d_in, const int* in_sizes, int n_in,
                              void* d_out, int out_size, void* d_ws, size_t ws_size,
                              hipStream_t stream)
{
    const float* x0    = (const float*)d_in[0];
    const float* w1    = (const float*)d_in[1];
    const float* b1    = (const float*)d_in[2];
    const float* g1    = (const float*)d_in[3];
    const float* be1   = (const float*)d_in[4];
    const float* m1    = (const float*)d_in[5];
    const float* v1    = (const float*)d_in[6];
    const float* w_off = (const float*)d_in[7];
    const float* b_off = (const float*)d_in[8];
    const float* w_mod = (const float*)d_in[9];
    const float* b_mod = (const float*)d_in[10];
    const float* w_def = (const float*)d_in[11];
    const float* b_def = (const float*)d_in[12];
    const float* g2    = (const float*)d_in[13];
    const float* be2   = (const float*)d_in[14];
    const float* m2    = (const float*)d_in[15];
    const float* v2    = (const float*)d_in[16];
    const float* w_ds  = (const float*)d_in[17];
    const float* b_ds  = (const float*)d_in[18];
    const float* g3    = (const float*)d_in[19];
    const float* be3   = (const float*)d_in[20];
    const float* m3    = (const float*)d_in[21];
    const float* v3    = (const float*)d_in[22];

    char* wsp = (char*)d_ws;
    auto alloc = [&](size_t bytes) { char* r = wsp; wsp += (bytes + 255) & ~(size_t)255; return r; };
    const size_t szX0 = (size_t)NN * 66 * 66 * 128 * 2;
    const size_t szX1 = (size_t)NN * 67 * 67 * 128 * 2;
    u16*   Xpad0  = (u16*)alloc(szX0);
    u16*   Xpad1  = (u16*)alloc(szX1);
    u16*   Hpad   = (u16*)alloc(szX1);            // sized for 67x67
    float* OFFMSK = (float*)alloc((size_t)16900 * 32 * 4);
    u16*   S3     = (u16*)alloc((size_t)3 * 16900 * 128 * 2);
    float* T      = (float*)alloc((size_t)16900 * 128 * 4);
    u16*   Wb1    = (u16*)alloc((size_t)128 * 1152 * 2);
    u16*   Wbdef  = (u16*)alloc((size_t)128 * 1152 * 2);
    u16*   Wbom   = (u16*)alloc((size_t)32 * 1152 * 2);
    u16*   Wbds   = (u16*)alloc((size_t)128 * 128 * 2);
    float* biasOM = (float*)alloc(32 * 4);

    const u16* curX = Xpad0;
    for (int i = 0; i < 2; ++i) {
        int H = 64 + i, W = 64 + i;
        int HW = H * W, NHW = NN * HW;

        const float* w1i   = w1    + (size_t)i * CC * CC * 9;
        const float* b1i   = b1    + (size_t)i * CC;
        const float* g1i   = g1 + i * CC, *be1i = be1 + i * CC, *m1i = m1 + i * CC, *v1i = v1 + i * CC;
        const float* woffi = w_off + (size_t)i * 18 * CC * 9;
        const float* boffi = b_off + (size_t)i * 18;
        const float* wmodi = w_mod + (size_t)i * 9 * CC * 9;
        const float* bmodi = b_mod + (size_t)i * 9;
        const float* wdefi = w_def + (size_t)i * CC * CC * 9;
        const float* bdefi = b_def + (size_t)i * CC;
        const float* g2i   = g2 + i * CC, *be2i = be2 + i * CC, *m2i = m2 + i * CC, *v2i = v2 + i * CC;
        const float* wdsi  = w_ds  + (size_t)i * CC * CC;
        const float* bdsi  = b_ds  + (size_t)i * CC;
        const float* g3i   = g3 + i * CC, *be3i = be3 + i * CC, *m3i = m3 + i * CC, *v3i = v3 + i * CC;

        if (i == 0) {
            hipMemsetAsync((void*)Xpad0, 0, szX0, stream);
            hipMemsetAsync((void*)Xpad1, 0, szX1, stream);
            x0_to_nhwc<<<(NN * 64 * 64 * 16 + 255) / 256, 256, 0, stream>>>(x0, Xpad0);
        }
        hipMemsetAsync((void*)Hpad, 0, szX1, stream);

        int wtot = 128 * 1152 + 32 * 1152 + 128 * 128 + 32;
        wconv_k<<<(wtot + 255) / 256, 256, 0, stream>>>(w1i, woffi, wmodi, wdefi, wdsi,
                                                        boffi, bmodi, Wb1, Wbom, Wbdef, Wbds, biasOM);

        // h = relu(bn1(conv3x3(x)))  -> padded NHWC bf16
        conv3x3_mfma<1, 4, 2, 2, 0><<<(NHW + 31) / 32, 256, 0, stream>>>(
            curX, Wb1, b1i, g1i, be1i, m1i, v1i, Hpad, H, W);
        // off(18) + msk(9) fused conv -> OFFMSK f32 [pix][32]
        conv3x3_mfma<2, 2, 2, 1, 1><<<(NHW + 63) / 64, 256, 0, stream>>>(
            Hpad, Wbom, biasOM, nullptr, nullptr, nullptr, nullptr, OFFMSK, H, W);

        // deformable conv: 3 x (sample 3 taps -> K=384 accumulating GEMM)
        for (int t0 = 0; t0 < 9; t0 += 3) {
            dsample3_k<<<(3 * NHW * 16 + 255) / 256, 256, 0, stream>>>(Hpad, OFFMSK, S3, H, W, t0);
            gemm1x1_mfma<3, 0, false><<<(NHW + 31) / 32, 256, 0, stream>>>(
                S3, Wbdef + (size_t)t0 * 128, 1152, t0, bdefi,
                nullptr, nullptr, nullptr, nullptr, nullptr, nullptr, nullptr, nullptr, T, H, W);
        }
        // T = relu(bn2(T) + bn3(x*wds + bds))
        gemm1x1_mfma<1, 1, true><<<(NHW + 31) / 32, 256, 0, stream>>>(
            curX, Wbds, 128, 0, bdsi, g2i, be2i, m2i, v2i, g3i, be3i, m3i, v3i, T, H, W);

        // maxpool
        if (i == 0) {
            pool_k<0><<<(NN * 65 * 65 * 16 + 255) / 256, 256, 0, stream>>>(T, Xpad1, H, W);
        } else {
            pool_k<1><<<(NN * 66 * 66 * 16 + 255) / 256, 256, 0, stream>>>(T, d_out, H, W);
        }
        curX = Xpad1;
    }
}

// Round 3
// 172.495 us; speedup vs baseline: 11.4779x; 2.1077x over previous
//
#include <hip/hip_runtime.h>
#include <math.h>

constexpr int NN = 4;    // batch
constexpr int CC = 128;  // channels

typedef unsigned short u16;
typedef short bfrag __attribute__((ext_vector_type(8)));   // 8 bf16
typedef float facc  __attribute__((ext_vector_type(4)));   // 4 f32 acc

__device__ __forceinline__ float bf2f(u16 v) {
    unsigned u = ((unsigned)v) << 16; float f; __builtin_memcpy(&f, &u, 4); return f;
}
__device__ __forceinline__ u16 f2bf(float f) {
    unsigned u; __builtin_memcpy(&u, &f, 4);
    unsigned r = u + 0x7FFFu + ((u >> 16) & 1u);
    return (u16)(r >> 16);
}

typedef const __attribute__((address_space(1))) unsigned int gu32;
typedef __attribute__((address_space(3))) unsigned int lu32;
__device__ __forceinline__ void gload16(const u16* g, u16* l) {
    __builtin_amdgcn_global_load_lds((gu32*)g, (lu32*)l, 16, 0, 0);
}

// =====================================================================
// LDS-staged 3x3 conv GEMM. A: padded NHWC bf16 [NN][Hp][Wq][128].
// Wp: packed native-frag order [tap][cc][ob][lane][8] bf16 (bn1 folded for EPI0).
// EPI 0: relu(acc+bias) -> padded NHWC bf16 out. EPI 1: off/msk -> f32 [pix][32]
//        (oc>=18 gets 2*sigmoid).
// Geometry: 512 thr = 8 waves; BM = WM*MR*16 = 64; BN = NOB*16.
// =====================================================================
template<int WM, int WN, int MR, int NR, int NOB, int EPI>
__global__ __launch_bounds__(512)
void gconv_k(const u16* __restrict__ A, const u16* __restrict__ Wp,
             const float* __restrict__ bias, void* __restrict__ Out,
             int H, int W)
{
    constexpr int BM = WM * MR * 16;          // 64
    constexpr int TAPB = NOB * 2048;          // elems per tap slice of B
    constexpr int NBP = NOB / 2;              // 8KB staging passes for B
    __shared__ __align__(16) u16 As[2][BM * 128];
    __shared__ __align__(16) u16 Bs[2][TAPB];

    const int Hp = H + 2, Wq = W + 2, HW = H * W, NHW = NN * HW;
    const int tid = threadIdx.x, lane = tid & 63, wv = tid >> 6;
    const int wn = wv % WN, wm = wv / WN;
    const int colc = lane & 15, kg = lane >> 4;
    const int m_base = blockIdx.x * BM;

    // staging geometry: thread -> (row srow & srow+32, granule sg), source pre-swizzled
    const int sg = tid & 15, srow = tid >> 4;
    const int sgz8 = (sg ^ (srow & 7)) * 8;
    size_t soff[2];
#pragma unroll
    for (int pass = 0; pass < 2; ++pass) {
        int r = pass * 32 + srow;
        int pix = m_base + r; if (pix > NHW - 1) pix = NHW - 1;
        int n = pix / HW, rr = pix - n * HW, y = rr / W, x = rr - y * W;
        soff[pass] = ((size_t)(n * Hp + y) * Wq + x) * 128 + sgz8;
    }

    facc acc[MR][NR];
#pragma unroll
    for (int r = 0; r < MR; ++r)
#pragma unroll
        for (int q = 0; q < NR; ++q) acc[r][q] = (facc){0.f, 0.f, 0.f, 0.f};

    auto stage = [&](int buf, int tap) {
        int ty = tap / 3, tx = tap - ty * 3;
        size_t toff = (size_t)(ty * Wq + tx) * 128;
        gload16(A + soff[0] + toff, &As[buf][wv * 512]);
        gload16(A + soff[1] + toff, &As[buf][4096 + wv * 512]);
        const u16* bs = Wp + (size_t)tap * TAPB + tid * 8;
#pragma unroll
        for (int p = 0; p < NBP; ++p)
            gload16(bs + p * 4096, &Bs[buf][p * 4096 + wv * 512]);
    };

    stage(0, 0);
    __syncthreads();
#pragma unroll 1
    for (int t = 0; t < 9; ++t) {
        if (t < 8) stage((t + 1) & 1, t + 1);
        const u16* as = As[t & 1];
        const u16* bs = Bs[t & 1];
#pragma unroll
        for (int cc = 0; cc < 4; ++cc) {
            bfrag a[MR], b[NR];
#pragma unroll
            for (int r = 0; r < MR; ++r) {
                int m = wm * (MR * 16) + r * 16 + colc;
                a[r] = *(const bfrag*)&as[m * 128 + ((cc * 4 + kg) ^ (m & 7)) * 8];
            }
#pragma unroll
            for (int q = 0; q < NR; ++q) {
                int ob = wn * NR + q;
                b[q] = *(const bfrag*)&bs[((cc * NOB + ob) * 64 + lane) * 8];
            }
#pragma unroll
            for (int r = 0; r < MR; ++r)
#pragma unroll
                for (int q = 0; q < NR; ++q)
                    acc[r][q] = __builtin_amdgcn_mfma_f32_16x16x32_bf16(a[r], b[q], acc[r][q], 0, 0, 0);
        }
        __syncthreads();
    }

#pragma unroll
    for (int r = 0; r < MR; ++r) {
#pragma unroll
        for (int j = 0; j < 4; ++j) {
            int pix = m_base + wm * (MR * 16) + r * 16 + kg * 4 + j;
            if (pix >= NHW) continue;
#pragma unroll
            for (int q = 0; q < NR; ++q) {
                int oc = wn * (NR * 16) + q * 16 + colc;
                float val = acc[r][q][j] + bias[oc];
                if constexpr (EPI == 0) {
                    val = fmaxf(val, 0.f);
                    int n = pix / HW, rr = pix - n * HW, y = rr / W, x = rr - y * W;
                    ((u16*)Out)[((size_t)(n * Hp + y + 1) * Wq + x + 1) * 128 + oc] = f2bf(val);
                } else {
                    if (oc >= 18) val = 2.f / (1.f + expf(-val));
                    ((float*)Out)[(size_t)pix * 32 + oc] = val;
                }
            }
        }
    }
}

// =====================================================================
// Fused deformable conv: 9 sampled taps + residual "tap 9" (A=x, B=sc3*Wds),
// sc2 folded into Wdef. Epilogue: T = relu(acc + biasC).
// Wp: 10-tap pack. OM: f32 [pix][32] (0..17 off, 18..26 mask=2*sigmoid).
// =====================================================================
__global__ __launch_bounds__(512)
void deform_k(const u16* __restrict__ Hb, const u16* __restrict__ Xp,
              const float* __restrict__ OM, const u16* __restrict__ Wp,
              const float* __restrict__ biasC, float* __restrict__ T,
              int H, int W)
{
    constexpr int WM = 2, WN = 4, MR = 2, NR = 2, NOB = 8;
    constexpr int TAPB = NOB * 2048;
    __shared__ __align__(16) u16 As[2][64 * 128];
    __shared__ __align__(16) u16 Bs[2][TAPB];

    const int Hp = H + 2, Wq = W + 2, HW = H * W, NHW = NN * HW;
    const int tid = threadIdx.x, lane = tid & 63, wv = tid >> 6;
    const int wn = wv % WN, wm = wv / WN;
    const int colc = lane & 15, kg = lane >> 4;
    const int m_base = blockIdx.x * 64;

    const int sg = tid & 15, srow = tid >> 4;
    const int sgz8 = (sg ^ (srow & 7)) * 8;
    int ppix[2], pn[2], pyv[2], pxv[2];
    size_t soffX[2];
#pragma unroll
    for (int pass = 0; pass < 2; ++pass) {
        int r = pass * 32 + srow;
        int pix = m_base + r; if (pix > NHW - 1) pix = NHW - 1;
        int n = pix / HW, rr = pix - n * HW, y = rr / W, x = rr - y * W;
        ppix[pass] = pix; pn[pass] = n; pyv[pass] = y; pxv[pass] = x;
        soffX[pass] = ((size_t)(n * Hp + y + 1) * Wq + x + 1) * 128 + sgz8;
    }

    auto stageB = [&](int buf, int tap) {
        const u16* bs = Wp + (size_t)tap * TAPB + tid * 8;
#pragma unroll
        for (int p = 0; p < 4; ++p)
            gload16(bs + p * 4096, &Bs[buf][p * 4096 + wv * 512]);
    };
    auto stageA9 = [&](int buf) {
        gload16(Xp + soffX[0], &As[buf][wv * 512]);
        gload16(Xp + soffX[1], &As[buf][4096 + wv * 512]);
    };
    auto sample = [&](int buf, int k) {
        int ky = k / 3, kx = k - ky * 3;
#pragma unroll
        for (int pass = 0; pass < 2; ++pass) {
            int r = pass * 32 + srow;
            const float* om = OM + (size_t)ppix[pass] * 32;
            float dy = om[2 * k], dx = om[2 * k + 1], mm = om[18 + k];
            float py = (float)pyv[pass] - 1.f + (float)ky + dy;
            float px = (float)pxv[pass] - 1.f + (float)kx + dx;
            float fy = floorf(py), fx = floorf(px);
            int y0 = (int)fy, x0 = (int)fx;
            float wy = py - fy, wx = px - fx;
            bool y0v = (y0 >= 0) && (y0 < H), y1v = (y0 >= -1) && (y0 < H - 1);
            bool x0v = (x0 >= 0) && (x0 < W), x1v = (x0 >= -1) && (x0 < W - 1);
            int yc0 = min(max(y0, 0), H - 1), yc1 = min(max(y0 + 1, 0), H - 1);
            int xc0 = min(max(x0, 0), W - 1), xc1 = min(max(x0 + 1, 0), W - 1);
            float w00 = (1.f - wy) * (1.f - wx) * ((y0v && x0v) ? mm : 0.f);
            float w01 = (1.f - wy) * wx         * ((y0v && x1v) ? mm : 0.f);
            float w10 = wy * (1.f - wx)         * ((y1v && x0v) ? mm : 0.f);
            float w11 = wy * wx                 * ((y1v && x1v) ? mm : 0.f);
            const u16* hb = Hb + (size_t)pn[pass] * Hp * Wq * 128 + sg * 8;
            bfrag c00 = *(const bfrag*)(hb + ((size_t)(yc0 + 1) * Wq + xc0 + 1) * 128);
            bfrag c01 = *(const bfrag*)(hb + ((size_t)(yc0 + 1) * Wq + xc1 + 1) * 128);
            bfrag c10 = *(const bfrag*)(hb + ((size_t)(yc1 + 1) * Wq + xc0 + 1) * 128);
            bfrag c11 = *(const bfrag*)(hb + ((size_t)(yc1 + 1) * Wq + xc1 + 1) * 128);
            bfrag o;
#pragma unroll
            for (int j = 0; j < 8; ++j) {
                float f = w00 * bf2f((u16)c00[j]) + w01 * bf2f((u16)c01[j])
                        + w10 * bf2f((u16)c10[j]) + w11 * bf2f((u16)c11[j]);
                o[j] = (short)f2bf(f);
            }
            *(bfrag*)&As[buf][r * 128 + sgz8] = o;
        }
    };

    facc acc[MR][NR];
#pragma unroll
    for (int r = 0; r < MR; ++r)
#pragma unroll
        for (int q = 0; q < NR; ++q) acc[r][q] = (facc){0.f, 0.f, 0.f, 0.f};

    sample(0, 0); stageB(0, 0);
    __syncthreads();
#pragma unroll 1
    for (int t = 0; t < 10; ++t) {
        if (t < 9) {
            stageB((t + 1) & 1, t + 1);
            if (t < 8) sample((t + 1) & 1, t + 1);
            else       stageA9((t + 1) & 1);
        }
        const u16* as = As[t & 1];
        const u16* bs = Bs[t & 1];
#pragma unroll
        for (int cc = 0; cc < 4; ++cc) {
            bfrag a[MR], b[NR];
#pragma unroll
            for (int r = 0; r < MR; ++r) {
                int m = wm * 32 + r * 16 + colc;
                a[r] = *(const bfrag*)&as[m * 128 + ((cc * 4 + kg) ^ (m & 7)) * 8];
            }
#pragma unroll
            for (int q = 0; q < NR; ++q) {
                int ob = wn * NR + q;
                b[q] = *(const bfrag*)&bs[((cc * NOB + ob) * 64 + lane) * 8];
            }
#pragma unroll
            for (int r = 0; r < MR; ++r)
#pragma unroll
                for (int q = 0; q < NR; ++q)
                    acc[r][q] = __builtin_amdgcn_mfma_f32_16x16x32_bf16(a[r], b[q], acc[r][q], 0, 0, 0);
        }
        __syncthreads();
    }

#pragma unroll
    for (int r = 0; r < MR; ++r) {
#pragma unroll
        for (int j = 0; j < 4; ++j) {
            int pix = m_base + wm * 32 + r * 16 + kg * 4 + j;
            if (pix >= NHW) continue;
#pragma unroll
            for (int q = 0; q < NR; ++q) {
                int oc = wn * 32 + q * 16 + colc;
                T[(size_t)pix * 128 + oc] = fmaxf(acc[r][q][j] + biasC[oc], 0.f);
            }
        }
    }
}

// ---- maxpool 2x2 s1 pad1: T f32 [pix][128] -> padded NHWC bf16 / NCHW f32 --
template<int OUTMODE>
__global__ __launch_bounds__(256)
void pool_k(const float* __restrict__ T, void* __restrict__ Out, int H, int W)
{
    const int HW = H * W, Ho = H + 1, Wo = W + 1;
    int tot = NN * Ho * Wo * 16;
    int idx = blockIdx.x * 256 + threadIdx.x;
    if (idx >= tot) return;
    int cg = idx & 15; int t = idx >> 4;
    int ox = t % Wo; t /= Wo; int oy = t % Ho; int n = t / Ho;

    float mx[8];
#pragma unroll
    for (int j = 0; j < 8; ++j) mx[j] = -INFINITY;
#pragma unroll
    for (int d = 0; d < 2; ++d) {
        int iy = oy - 1 + d;
        if (iy < 0 || iy >= H) continue;
#pragma unroll
        for (int e = 0; e < 2; ++e) {
            int ix = ox - 1 + e;
            if (ix < 0 || ix >= W) continue;
            const float* src = T + ((size_t)(n * HW + iy * W + ix)) * 128 + cg * 8;
#pragma unroll
            for (int j = 0; j < 8; ++j) mx[j] = fmaxf(mx[j], src[j]);
        }
    }
    if constexpr (OUTMODE == 0) {
        int Hp2 = Ho + 2, Wp2 = Wo + 2;
        bfrag o;
#pragma unroll
        for (int j = 0; j < 8; ++j) o[j] = (short)f2bf(mx[j]);
        *(bfrag*)((u16*)Out + ((size_t)(n * Hp2 + oy + 1) * Wp2 + (ox + 1)) * 128 + cg * 8) = o;
    } else {
#pragma unroll
        for (int j = 0; j < 8; ++j) {
            int c = cg * 8 + j;
            ((float*)Out)[(((size_t)n * 128 + c) * Ho + oy) * Wo + ox] = mx[j];
        }
    }
}

// ---- x (NCHW f32) -> padded NHWC bf16 (64x64 -> 66x66) -------------------
__global__ __launch_bounds__(256)
void x0_to_nhwc(const float* __restrict__ x0, u16* __restrict__ Xp)
{
    int idx = blockIdx.x * 256 + threadIdx.x;
    if (idx >= NN * 64 * 64 * 16) return;
    int cg = idx & 15; int t = idx >> 4;
    int x = t & 63; t >>= 6; int y = t & 63; int n = t >> 6;
    bfrag o;
#pragma unroll
    for (int j = 0; j < 8; ++j) {
        int c = cg * 8 + j;
        o[j] = (short)f2bf(x0[(((size_t)n * 128 + c) * 64 + y) * 64 + x]);
    }
    *(bfrag*)(Xp + ((size_t)(n * 66 + y + 1) * 66 + (x + 1)) * 128 + cg * 8) = o;
}

// ---- weight prep: pack to native-frag order, fold BN ---------------------
// pack elem e: j=e&7, lane=(e>>3)&63, then ob, cc, tap; oc=ob*16+(lane&15),
// c = cc*32 + (lane>>4)*8 + j.
__global__ __launch_bounds__(256)
void wprep_k(const float* __restrict__ w1, const float* __restrict__ b1,
             const float* __restrict__ g1, const float* __restrict__ be1,
             const float* __restrict__ m1, const float* __restrict__ v1,
             const float* __restrict__ w_off, const float* __restrict__ b_off,
             const float* __restrict__ w_mod, const float* __restrict__ b_mod,
             const float* __restrict__ w_def, const float* __restrict__ b_def,
             const float* __restrict__ g2, const float* __restrict__ be2,
             const float* __restrict__ m2, const float* __restrict__ v2,
             const float* __restrict__ w_ds, const float* __restrict__ b_ds,
             const float* __restrict__ g3, const float* __restrict__ be3,
             const float* __restrict__ m3, const float* __restrict__ v3,
             u16* __restrict__ Wb1p, u16* __restrict__ Wbomp, u16* __restrict__ Wbdp,
             float* __restrict__ bias1f, float* __restrict__ biasOM, float* __restrict__ biasC)
{
    const int C1 = 9 * 4 * 8 * 512;   // 147456
    const int C2 = 9 * 4 * 2 * 512;   // 36864
    const int C3 = 10 * 4 * 8 * 512;  // 163840
    int idx = blockIdx.x * 256 + threadIdx.x;
    if (idx < 2 * C1) {
        int inst = idx / C1, e = idx - inst * C1;
        int j = e & 7, lane = (e >> 3) & 63, rest = e >> 9;
        int ob = rest & 7; rest >>= 3; int cc = rest & 3; int tap = rest >> 2;
        int oc = ob * 16 + (lane & 15), c = cc * 32 + (lane >> 4) * 8 + j;
        float sc = g1[inst * 128 + oc] * rsqrtf(v1[inst * 128 + oc] + 1e-5f);
        Wb1p[idx] = f2bf(sc * w1[(((size_t)inst * 128 + oc) * 128 + c) * 9 + tap]);
        return;
    }
    idx -= 2 * C1;
    if (idx < 2 * C2) {
        int inst = idx / C2, e = idx - inst * C2;
        int j = e & 7, lane = (e >> 3) & 63, rest = e >> 9;
        int ob = rest & 1; rest >>= 1; int cc = rest & 3; int tap = rest >> 2;
        int oc = ob * 16 + (lane & 15), c = cc * 32 + (lane >> 4) * 8 + j;
        float v = 0.f;
        if (oc < 18)      v = w_off[(((size_t)inst * 18 + oc) * 128 + c) * 9 + tap];
        else if (oc < 27) v = w_mod[(((size_t)inst * 9 + (oc - 18)) * 128 + c) * 9 + tap];
        Wbomp[inst * C2 + e] = f2bf(v);
        return;
    }
    idx -= 2 * C2;
    if (idx < 2 * C3) {
        int inst = idx / C3, e = idx - inst * C3;
        int j = e & 7, lane = (e >> 3) & 63, rest = e >> 9;
        int ob = rest & 7; rest >>= 3; int cc = rest & 3; int tap = rest >> 2;
        int oc = ob * 16 + (lane & 15), c = cc * 32 + (lane >> 4) * 8 + j;
        float val;
        if (tap < 9) {
            float sc2 = g2[inst * 128 + oc] * rsqrtf(v2[inst * 128 + oc] + 1e-5f);
            val = sc2 * w_def[(((size_t)inst * 128 + oc) * 128 + c) * 9 + tap];
        } else {
            float sc3 = g3[inst * 128 + oc] * rsqrtf(v3[inst * 128 + oc] + 1e-5f);
            val = sc3 * w_ds[((size_t)inst * 128 + oc) * 128 + c];
        }
        Wbdp[inst * C3 + e] = f2bf(val);
        return;
    }
    idx -= 2 * C3;
    if (idx < 2 * 288) {
        int inst = idx / 288, r = idx - inst * 288;
        if (r < 128) {
            int oc = r, o = inst * 128 + oc;
            float sc = g1[o] * rsqrtf(v1[o] + 1e-5f);
            bias1f[o] = sc * b1[o] + be1[o] - m1[o] * sc;
        } else if (r < 160) {
            int oc = r - 128;
            float v = 0.f;
            if (oc < 18)      v = b_off[inst * 18 + oc];
            else if (oc < 27) v = b_mod[inst * 9 + (oc - 18)];
            biasOM[inst * 32 + oc] = v;
        } else {
            int oc = r - 160, o = inst * 128 + oc;
            float sc2 = g2[o] * rsqrtf(v2[o] + 1e-5f);
            float sc3 = g3[o] * rsqrtf(v3[o] + 1e-5f);
            biasC[o] = sc2 * b_def[o] + (be2[o] - m2[o] * sc2)
                     + sc3 * b_ds[o] + (be3[o] - m3[o] * sc3);
        }
    }
}

extern "C" void kernel_launch(void* const* d_in, const int* in_sizes, int n_in,
                              void* d_out, int out_size, void* d_ws, size_t ws_size,
                              hipStream_t stream)
{
    const float* x0    = (const float*)d_in[0];
    const float* w1    = (const float*)d_in[1];
    const float* b1    = (const float*)d_in[2];
    const float* g1    = (const float*)d_in[3];
    const float* be1   = (const float*)d_in[4];
    const float* m1    = (const float*)d_in[5];
    const float* v1    = (const float*)d_in[6];
    const float* w_off = (const float*)d_in[7];
    const float* b_off = (const float*)d_in[8];
    const float* w_mod = (const float*)d_in[9];
    const float* b_mod = (const float*)d_in[10];
    const float* w_def = (const float*)d_in[11];
    const float* b_def = (const float*)d_in[12];
    const float* g2    = (const float*)d_in[13];
    const float* be2   = (const float*)d_in[14];
    const float* m2    = (const float*)d_in[15];
    const float* v2    = (const float*)d_in[16];
    const float* w_ds  = (const float*)d_in[17];
    const float* b_ds  = (const float*)d_in[18];
    const float* g3    = (const float*)d_in[19];
    const float* be3   = (const float*)d_in[20];
    const float* m3    = (const float*)d_in[21];
    const float* v3    = (const float*)d_in[22];

    const int C1 = 147456, C2 = 36864, C3 = 163840;
    char* wsp = (char*)d_ws;
    auto alloc = [&](size_t bytes) { char* r = wsp; wsp += (bytes + 255) & ~(size_t)255; return r; };
    const size_t szX0 = (size_t)NN * 66 * 66 * 128 * 2;
    const size_t szX1 = (size_t)NN * 67 * 67 * 128 * 2;
    u16*   Xpad0  = (u16*)alloc(szX0);
    u16*   Xpad1  = (u16*)alloc(szX1);
    u16*   Hpad   = (u16*)alloc(szX1);
    float* OFFMSK = (float*)alloc((size_t)16900 * 32 * 4);
    float* T      = (float*)alloc((size_t)16900 * 128 * 4);
    u16*   Wb1p   = (u16*)alloc((size_t)2 * C1 * 2);
    u16*   Wbomp  = (u16*)alloc((size_t)2 * C2 * 2);
    u16*   Wbdp   = (u16*)alloc((size_t)2 * C3 * 2);
    float* bias1f = (float*)alloc(2 * 128 * 4);
    float* biasOM = (float*)alloc(2 * 32 * 4);
    float* biasC  = (float*)alloc(2 * 128 * 4);

    // ---- prologue: layout conversion + weight packing (all instances) ----
    hipMemsetAsync((void*)Xpad0, 0, szX0, stream);
    hipMemsetAsync((void*)Xpad1, 0, szX1, stream);
    x0_to_nhwc<<<(NN * 64 * 64 * 16 + 255) / 256, 256, 0, stream>>>(x0, Xpad0);
    int ptot = 2 * C1 + 2 * C2 + 2 * C3 + 2 * 288;
    wprep_k<<<(ptot + 255) / 256, 256, 0, stream>>>(
        w1, b1, g1, be1, m1, v1, w_off, b_off, w_mod, b_mod, w_def, b_def,
        g2, be2, m2, v2, w_ds, b_ds, g3, be3, m3, v3,
        Wb1p, Wbomp, Wbdp, bias1f, biasOM, biasC);

    const u16* curX = Xpad0;
    for (int i = 0; i < 2; ++i) {
        int H = 64 + i, W = 64 + i;
        int NHW = NN * H * W;
        int gx = (NHW + 63) / 64;

        hipMemsetAsync((void*)Hpad, 0, szX1, stream);
        // h = relu(bn1(conv3x3(x)))
        gconv_k<2, 4, 2, 2, 8, 0><<<gx, 512, 0, stream>>>(
            curX, Wb1p + (size_t)i * C1, bias1f + i * 128, Hpad, H, W);
        // off(18) + msk(9, 2*sigmoid) -> OFFMSK [pix][32]
        gconv_k<4, 2, 1, 1, 2, 1><<<gx, 512, 0, stream>>>(
            Hpad, Wbomp + (size_t)i * C2, biasOM + i * 32, OFFMSK, H, W);
        // fused deformable conv + residual + bn2/bn3 + relu
        deform_k<<<gx, 512, 0, stream>>>(
            Hpad, curX, OFFMSK, Wbdp + (size_t)i * C3, biasC + i * 128, T, H, W);
        // maxpool
        if (i == 0) {
            pool_k<0><<<(NN * 65 * 65 * 16 + 255) / 256, 256, 0, stream>>>(T, Xpad1, H, W);
        } else {
            pool_k<1><<<(NN * 66 * 66 * 16 + 255) / 256, 256, 0, stream>>>(T, d_out, H, W);
        }
        curX = Xpad1;
    }
}

// Round 5
// 169.120 us; speedup vs baseline: 11.7069x; 1.0200x over previous
//
#include <hip/hip_runtime.h>
#include <math.h>

constexpr int NN = 4;    // batch
constexpr int CC = 128;  // channels

typedef unsigned short u16;
typedef short bfrag __attribute__((ext_vector_type(8)));   // 8 bf16
typedef float facc  __attribute__((ext_vector_type(4)));   // 4 f32 acc

__device__ __forceinline__ float bf2f(u16 v) {
    unsigned u = ((unsigned)v) << 16; float f; __builtin_memcpy(&f, &u, 4); return f;
}
__device__ __forceinline__ u16 f2bf(float f) {
    unsigned u; __builtin_memcpy(&u, &f, 4);
    unsigned r = u + 0x7FFFu + ((u >> 16) & 1u);
    return (u16)(r >> 16);
}

typedef const __attribute__((address_space(1))) unsigned int gu32;
typedef __attribute__((address_space(3))) unsigned int lu32;
__device__ __forceinline__ void gload16(const u16* g, u16* l) {
    __builtin_amdgcn_global_load_lds((gu32*)g, (lu32*)l, 16, 0, 0);
}

// =====================================================================
// Halo-LDS 3x3 conv GEMM. A: padded NHWC bf16 [NN][Hp][Wq][128].
// Block = 64 linear pixels of one image. Stage 4 padded rows (swizzled
// granules) once; K-loop is pure LDS + register-B (prefetched) + MFMA,
// NO barriers inside. Wp: [tap][cc][ob][lane][8] bf16.
// EPI 0: relu(acc+bias) -> padded NHWC bf16. EPI 1: f32 [pix][32], oc>=18
// gets 2*sigmoid.
// =====================================================================
template<int WM, int WN, int MR, int NR, int NOB, int EPI>
__global__ __launch_bounds__(512)
void gconv_h(const u16* __restrict__ A, const u16* __restrict__ Wp,
             const float* __restrict__ bias, void* __restrict__ Out,
             int H, int W, int npb)
{
    constexpr int HALOW = 68;
    __shared__ __align__(16) u16 halo[4 * HALOW * 128];    // 69632 B

    const int Hp = H + 2, Wq = W + 2, HW = H * W;
    const int tid = threadIdx.x, lane = tid & 63, wv = tid >> 6;
    const int wn = wv % WN, wm = wv / WN;
    const int colc = lane & 15, kg = lane >> 4;
    const int n = blockIdx.x / npb;
    const int pib = (blockIdx.x - n * npb) * 64;
    const int ymin = pib / W;

    // ---- stage 4 padded rows [ymin .. ymin+3] (clamped), swizzled granules
    {
        const u16* Abase = A + (size_t)n * Hp * Wq * 128;
        for (int c = wv; c < 4 * HALOW / 4; c += 8) {     // 68 chunks of 1KB
            int o = c * 512 + lane * 8;
            int r = o / (HALOW * 128);
            int e = o - r * (HALOW * 128);
            int x = e >> 7;
            int g = (e >> 3) & 15;
            int xs = x < Wq ? x : Wq - 1;
            int pr = ymin + r; if (pr > Hp - 1) pr = Hp - 1;
            const u16* src = Abase + ((size_t)pr * Wq + xs) * 128 + (g ^ (x & 7)) * 8;
            gload16(src, &halo[c * 512]);
        }
    }
    __syncthreads();

    // per-lane A geometry
    int dyr[MR], axr[MR];
#pragma unroll
    for (int r = 0; r < MR; ++r) {
        int m = wm * (MR * 16) + r * 16 + colc;
        int pixl = pib + m; if (pixl > HW - 1) pixl = HW - 1;
        int y = pixl / W;
        dyr[r] = y - ymin; axr[r] = pixl - y * W;
    }

    auto wfrag = [&](int tap, int cc, int q) -> const bfrag* {
        return (const bfrag*)(Wp + (size_t)tap * (NOB * 2048)
                              + ((cc * NOB + wn * NR + q) * 64 + lane) * 8);
    };

    bfrag bc[4][NR];
#pragma unroll
    for (int cc = 0; cc < 4; ++cc)
#pragma unroll
        for (int q = 0; q < NR; ++q) bc[cc][q] = *wfrag(0, cc, q);

    facc acc[MR][NR];
#pragma unroll
    for (int r = 0; r < MR; ++r)
#pragma unroll
        for (int q = 0; q < NR; ++q) acc[r][q] = (facc){0.f, 0.f, 0.f, 0.f};

#pragma unroll 1
    for (int t = 0; t < 9; ++t) {
        int ty = t / 3, tx = t - ty * 3;
        bfrag bn_[4][NR];
        if (t < 8) {
#pragma unroll
            for (int cc = 0; cc < 4; ++cc)
#pragma unroll
                for (int q = 0; q < NR; ++q) bn_[cc][q] = *wfrag(t + 1, cc, q);
        }
#pragma unroll
        for (int cc = 0; cc < 4; ++cc) {
            bfrag a[MR];
#pragma unroll
            for (int r = 0; r < MR; ++r) {
                int xx = axr[r] + tx;
                a[r] = *(const bfrag*)&halo[((dyr[r] + ty) * HALOW + xx) * 128
                                            + ((cc * 4 + kg) ^ (xx & 7)) * 8];
            }
#pragma unroll
            for (int r = 0; r < MR; ++r)
#pragma unroll
                for (int q = 0; q < NR; ++q)
                    acc[r][q] = __builtin_amdgcn_mfma_f32_16x16x32_bf16(a[r], bc[cc][q], acc[r][q], 0, 0, 0);
        }
        if (t < 8) {
#pragma unroll
            for (int cc = 0; cc < 4; ++cc)
#pragma unroll
                for (int q = 0; q < NR; ++q) bc[cc][q] = bn_[cc][q];
        }
    }

#pragma unroll
    for (int r = 0; r < MR; ++r) {
#pragma unroll
        for (int j = 0; j < 4; ++j) {
            int m = wm * (MR * 16) + r * 16 + kg * 4 + j;
            int pixl = pib + m;
            if (pixl >= HW) continue;
#pragma unroll
            for (int q = 0; q < NR; ++q) {
                int oc = wn * (NR * 16) + q * 16 + colc;
                float val = acc[r][q][j] + bias[oc];
                if constexpr (EPI == 0) {
                    val = fmaxf(val, 0.f);
                    int y = pixl / W, x = pixl - y * W;
                    ((u16*)Out)[((size_t)(n * Hp + y + 1) * Wq + x + 1) * 128 + oc] = f2bf(val);
                } else {
                    if (oc >= 18) val = 2.f / (1.f + expf(-val));
                    ((float*)Out)[((size_t)n * HW + pixl) * 32 + oc] = val;
                }
            }
        }
    }
}

// =====================================================================
// Fused deformable conv, halo-LDS version. Stage 7 unpadded h-rows +
// OM slice once; 10 taps (9 sampled + residual from Xp) of LDS-local
// sample -> swizzled As -> MFMA with register-B. One barrier per tap.
// Corners outside the 7-row window (rare: |dy|>~1) fall back to a
// global read of padded h -> exact for ANY offset magnitude.
// =====================================================================
__global__ __launch_bounds__(512)
void deform_h(const u16* __restrict__ Hb, const u16* __restrict__ Xp,
              const float* __restrict__ OM, const u16* __restrict__ Wp,
              const float* __restrict__ biasC, float* __restrict__ T,
              int H, int W, int npb)
{
    constexpr int HALOW = 68;
    __shared__ __align__(16) u16 halo[7 * HALOW * 128];    // 121856 B
    __shared__ __align__(16) u16 As2[2][8192];             // 32768 B
    __shared__ __align__(16) float om[2048];               // 8192 B

    const int Hp = H + 2, Wq = W + 2, HW = H * W;
    const int tid = threadIdx.x, lane = tid & 63, wv = tid >> 6;
    const int wn = wv % 4, wm = wv / 4;                    // WN=4, WM=2
    const int colc = lane & 15, kg = lane >> 4;
    const int n = blockIdx.x / npb;
    const int pib = (blockIdx.x - n * npb) * 64;
    const int ymin = pib / W;
    int r0 = ymin - 2; if (r0 < 0) r0 = 0; if (r0 > H - 7) r0 = H - 7;
    const u16* Hbase = Hb + (size_t)n * Hp * Wq * 128;

    // ---- stage halo: 7 rows x HALOW cols (col clamped to W-1), linear
    {
        for (int c = wv; c < 119; c += 8) {                // 119 chunks of 1KB
            int o = c * 512 + lane * 8;
            int r = o / (HALOW * 128);
            int e = o - r * (HALOW * 128);
            int x = e >> 7;
            int g8 = e & 127;
            int xs = x < W ? x : W - 1;
            const u16* src = Hbase + ((size_t)(r0 + r + 1) * Wq + xs + 1) * 128 + g8;
            gload16(src, &halo[c * 512]);
        }
        // OM slice: 64 px * 32 f32 = 8KB
        const u16* osrc = (const u16*)(OM + ((size_t)n * HW + pib) * 32) + wv * 512 + lane * 8;
        gload16(osrc, (u16*)om + wv * 512);
    }
    __syncthreads();

    // sampling thread geometry
    const int sg = tid & 15, srow = tid >> 4;
    const int sgz8 = (sg ^ (srow & 7)) * 8;
    int spy[2], spx[2];
    size_t soffX[2];
#pragma unroll
    for (int pass = 0; pass < 2; ++pass) {
        int pixl = pib + pass * 32 + srow; if (pixl > HW - 1) pixl = HW - 1;
        int y = pixl / W, x = pixl - y * W;
        spy[pass] = y; spx[pass] = x;
        soffX[pass] = ((size_t)(n * Hp + y + 1) * Wq + x + 1) * 128 + sgz8;
    }

    auto corner = [&](int yc, int xc) -> bfrag {
        int ry = yc - r0;
        if (ry >= 0 && ry < 7)
            return *(const bfrag*)&halo[(ry * HALOW + xc) * 128 + sg * 8];
        // rare fallback: offset pushed the sample outside the staged window
        return *(const bfrag*)(Hbase + ((size_t)(yc + 1) * Wq + xc + 1) * 128 + sg * 8);
    };

    auto sample = [&](int buf, int k) {
        int ky = k / 3, kx = k - ky * 3;
#pragma unroll
        for (int pass = 0; pass < 2; ++pass) {
            int r = pass * 32 + srow;
            const float* omp = om + r * 32;
            float dy = omp[2 * k], dx = omp[2 * k + 1], mm = omp[18 + k];
            float py = (float)spy[pass] - 1.f + (float)ky + dy;
            float px = (float)spx[pass] - 1.f + (float)kx + dx;
            float fy = floorf(py), fx = floorf(px);
            int y0 = (int)fy, x0 = (int)fx;
            float wy = py - fy, wx = px - fx;
            bool y0v = (y0 >= 0) && (y0 < H), y1v = (y0 >= -1) && (y0 < H - 1);
            bool x0v = (x0 >= 0) && (x0 < W), x1v = (x0 >= -1) && (x0 < W - 1);
            int yc0 = min(max(y0, 0), H - 1), yc1 = min(max(y0 + 1, 0), H - 1);
            int xc0 = min(max(x0, 0), W - 1), xc1 = min(max(x0 + 1, 0), W - 1);
            float w00 = (1.f - wy) * (1.f - wx) * ((y0v && x0v) ? mm : 0.f);
            float w01 = (1.f - wy) * wx         * ((y0v && x1v) ? mm : 0.f);
            float w10 = wy * (1.f - wx)         * ((y1v && x0v) ? mm : 0.f);
            float w11 = wy * wx                 * ((y1v && x1v) ? mm : 0.f);
            bfrag c00 = corner(yc0, xc0);
            bfrag c01 = corner(yc0, xc1);
            bfrag c10 = corner(yc1, xc0);
            bfrag c11 = corner(yc1, xc1);
            bfrag o;
#pragma unroll
            for (int j = 0; j < 8; ++j) {
                float f = w00 * bf2f((u16)c00[j]) + w01 * bf2f((u16)c01[j])
                        + w10 * bf2f((u16)c10[j]) + w11 * bf2f((u16)c11[j]);
                o[j] = (short)f2bf(f);
            }
            *(bfrag*)&As2[buf][r * 128 + sgz8] = o;
        }
    };
    auto stageA9 = [&](int buf) {
        gload16(Xp + soffX[0], &As2[buf][wv * 512]);
        gload16(Xp + soffX[1], &As2[buf][4096 + wv * 512]);
    };

    auto wfrag = [&](int tap, int cc, int q) -> const bfrag* {
        return (const bfrag*)(Wp + (size_t)tap * 16384
                              + ((cc * 8 + wn * 2 + q) * 64 + lane) * 8);
    };

    bfrag bc[4][2];
#pragma unroll
    for (int cc = 0; cc < 4; ++cc)
#pragma unroll
        for (int q = 0; q < 2; ++q) bc[cc][q] = *wfrag(0, cc, q);

    facc acc[2][2];
#pragma unroll
    for (int r = 0; r < 2; ++r)
#pragma unroll
        for (int q = 0; q < 2; ++q) acc[r][q] = (facc){0.f, 0.f, 0.f, 0.f};

    sample(0, 0);
    __syncthreads();

#pragma unroll 1
    for (int t = 0; t < 10; ++t) {
        bfrag bn_[4][2];
        if (t < 9) {
#pragma unroll
            for (int cc = 0; cc < 4; ++cc)
#pragma unroll
                for (int q = 0; q < 2; ++q) bn_[cc][q] = *wfrag(t + 1, cc, q);
            if (t < 8) sample((t + 1) & 1, t + 1);
            else       stageA9((t + 1) & 1);
        }
        const u16* as = As2[t & 1];
#pragma unroll
        for (int cc = 0; cc < 4; ++cc) {
            bfrag a[2];
#pragma unroll
            for (int r = 0; r < 2; ++r) {
                int m = wm * 32 + r * 16 + colc;
                a[r] = *(const bfrag*)&as[m * 128 + ((cc * 4 + kg) ^ (m & 7)) * 8];
            }
#pragma unroll
            for (int r = 0; r < 2; ++r)
#pragma unroll
                for (int q = 0; q < 2; ++q)
                    acc[r][q] = __builtin_amdgcn_mfma_f32_16x16x32_bf16(a[r], bc[cc][q], acc[r][q], 0, 0, 0);
        }
        if (t < 9) {
#pragma unroll
            for (int cc = 0; cc < 4; ++cc)
#pragma unroll
                for (int q = 0; q < 2; ++q) bc[cc][q] = bn_[cc][q];
        }
        __syncthreads();
    }

#pragma unroll
    for (int r = 0; r < 2; ++r) {
#pragma unroll
        for (int j = 0; j < 4; ++j) {
            int m = wm * 32 + r * 16 + kg * 4 + j;
            int pixl = pib + m;
            if (pixl >= HW) continue;
#pragma unroll
            for (int q = 0; q < 2; ++q) {
                int oc = wn * 32 + q * 16 + colc;
                T[((size_t)n * HW + pixl) * 128 + oc] = fmaxf(acc[r][q][j] + biasC[oc], 0.f);
            }
        }
    }
}

// ---- maxpool 2x2 s1 pad1: T f32 [pix][128] -> padded NHWC bf16 / NCHW f32 --
template<int OUTMODE>
__global__ __launch_bounds__(256)
void pool_k(const float* __restrict__ T, void* __restrict__ Out, int H, int W)
{
    const int HW = H * W, Ho = H + 1, Wo = W + 1;
    int tot = NN * Ho * Wo * 16;
    int idx = blockIdx.x * 256 + threadIdx.x;
    if (idx >= tot) return;
    int cg = idx & 15; int t = idx >> 4;
    int ox = t % Wo; t /= Wo; int oy = t % Ho; int n = t / Ho;

    float mx[8];
#pragma unroll
    for (int j = 0; j < 8; ++j) mx[j] = -INFINITY;
#pragma unroll
    for (int d = 0; d < 2; ++d) {
        int iy = oy - 1 + d;
        if (iy < 0 || iy >= H) continue;
#pragma unroll
        for (int e = 0; e < 2; ++e) {
            int ix = ox - 1 + e;
            if (ix < 0 || ix >= W) continue;
            const float* src = T + ((size_t)(n * HW + iy * W + ix)) * 128 + cg * 8;
#pragma unroll
            for (int j = 0; j < 8; ++j) mx[j] = fmaxf(mx[j], src[j]);
        }
    }
    if constexpr (OUTMODE == 0) {
        int Hp2 = Ho + 2, Wp2 = Wo + 2;
        bfrag o;
#pragma unroll
        for (int j = 0; j < 8; ++j) o[j] = (short)f2bf(mx[j]);
        *(bfrag*)((u16*)Out + ((size_t)(n * Hp2 + oy + 1) * Wp2 + (ox + 1)) * 128 + cg * 8) = o;
    } else {
#pragma unroll
        for (int j = 0; j < 8; ++j) {
            int c = cg * 8 + j;
            ((float*)Out)[(((size_t)n * 128 + c) * Ho + oy) * Wo + ox] = mx[j];
        }
    }
}

// ---- x (NCHW f32) -> padded NHWC bf16 (64x64 -> 66x66) -------------------
__global__ __launch_bounds__(256)
void x0_to_nhwc(const float* __restrict__ x0, u16* __restrict__ Xp)
{
    int idx = blockIdx.x * 256 + threadIdx.x;
    if (idx >= NN * 64 * 64 * 16) return;
    int cg = idx & 15; int t = idx >> 4;
    int x = t & 63; t >>= 6; int y = t & 63; int n = t >> 6;
    bfrag o;
#pragma unroll
    for (int j = 0; j < 8; ++j) {
        int c = cg * 8 + j;
        o[j] = (short)f2bf(x0[(((size_t)n * 128 + c) * 64 + y) * 64 + x]);
    }
    *(bfrag*)(Xp + ((size_t)(n * 66 + y + 1) * 66 + (x + 1)) * 128 + cg * 8) = o;
}

// ---- weight prep: pack to native-frag order, fold BN ---------------------
__global__ __launch_bounds__(256)
void wprep_k(const float* __restrict__ w1, const float* __restrict__ b1,
             const float* __restrict__ g1, const float* __restrict__ be1,
             const float* __restrict__ m1, const float* __restrict__ v1,
             const float* __restrict__ w_off, const float* __restrict__ b_off,
             const float* __restrict__ w_mod, const float* __restrict__ b_mod,
             const float* __restrict__ w_def, const float* __restrict__ b_def,
             const float* __restrict__ g2, const float* __restrict__ be2,
             const float* __restrict__ m2, const float* __restrict__ v2,
             const float* __restrict__ w_ds, const float* __restrict__ b_ds,
             const float* __restrict__ g3, const float* __restrict__ be3,
             const float* __restrict__ m3, const float* __restrict__ v3,
             u16* __restrict__ Wb1p, u16* __restrict__ Wbomp, u16* __restrict__ Wbdp,
             float* __restrict__ bias1f, float* __restrict__ biasOM, float* __restrict__ biasC)
{
    const int C1 = 9 * 4 * 8 * 512;   // 147456
    const int C2 = 9 * 4 * 2 * 512;   // 36864
    const int C3 = 10 * 4 * 8 * 512;  // 163840
    int idx = blockIdx.x * 256 + threadIdx.x;
    if (idx < 2 * C1) {
        int inst = idx / C1, e = idx - inst * C1;
        int j = e & 7, lane = (e >> 3) & 63, rest = e >> 9;
        int ob = rest & 7; rest >>= 3; int cc = rest & 3; int tap = rest >> 2;
        int oc = ob * 16 + (lane & 15), c = cc * 32 + (lane >> 4) * 8 + j;
        float sc = g1[inst * 128 + oc] * rsqrtf(v1[inst * 128 + oc] + 1e-5f);
        Wb1p[idx] = f2bf(sc * w1[(((size_t)inst * 128 + oc) * 128 + c) * 9 + tap]);
        return;
    }
    idx -= 2 * C1;
    if (idx < 2 * C2) {
        int inst = idx / C2, e = idx - inst * C2;
        int j = e & 7, lane = (e >> 3) & 63, rest = e >> 9;
        int ob = rest & 1; rest >>= 1; int cc = rest & 3; int tap = rest >> 2;
        int oc = ob * 16 + (lane & 15), c = cc * 32 + (lane >> 4) * 8 + j;
        float v = 0.f;
        if (oc < 18)      v = w_off[(((size_t)inst * 18 + oc) * 128 + c) * 9 + tap];
        else if (oc < 27) v = w_mod[(((size_t)inst * 9 + (oc - 18)) * 128 + c) * 9 + tap];
        Wbomp[inst * C2 + e] = f2bf(v);
        return;
    }
    idx -= 2 * C2;
    if (idx < 2 * C3) {
        int inst = idx / C3, e = idx - inst * C3;
        int j = e & 7, lane = (e >> 3) & 63, rest = e >> 9;
        int ob = rest & 7; rest >>= 3; int cc = rest & 3; int tap = rest >> 2;
        int oc = ob * 16 + (lane & 15), c = cc * 32 + (lane >> 4) * 8 + j;
        float val;
        if (tap < 9) {
            float sc2 = g2[inst * 128 + oc] * rsqrtf(v2[inst * 128 + oc] + 1e-5f);
            val = sc2 * w_def[(((size_t)inst * 128 + oc) * 128 + c) * 9 + tap];
        } else {
            float sc3 = g3[inst * 128 + oc] * rsqrtf(v3[inst * 128 + oc] + 1e-5f);
            val = sc3 * w_ds[((size_t)inst * 128 + oc) * 128 + c];
        }
        Wbdp[inst * C3 + e] = f2bf(val);
        return;
    }
    idx -= 2 * C3;
    if (idx < 2 * 288) {
        int inst = idx / 288, r = idx - inst * 288;
        if (r < 128) {
            int oc = r, o = inst * 128 + oc;
            float sc = g1[o] * rsqrtf(v1[o] + 1e-5f);
            bias1f[o] = sc * b1[o] + be1[o] - m1[o] * sc;
        } else if (r < 160) {
            int oc = r - 128;
            float v = 0.f;
            if (oc < 18)      v = b_off[inst * 18 + oc];
            else if (oc < 27) v = b_mod[inst * 9 + (oc - 18)];
            biasOM[inst * 32 + oc] = v;
        } else {
            int oc = r - 160, o = inst * 128 + oc;
            float sc2 = g2[o] * rsqrtf(v2[o] + 1e-5f);
            float sc3 = g3[o] * rsqrtf(v3[o] + 1e-5f);
            biasC[o] = sc2 * b_def[o] + (be2[o] - m2[o] * sc2)
                     + sc3 * b_ds[o] + (be3[o] - m3[o] * sc3);
        }
    }
}

extern "C" void kernel_launch(void* const* d_in, const int* in_sizes, int n_in,
                              void* d_out, int out_size, void* d_ws, size_t ws_size,
                              hipStream_t stream)
{
    const float* x0    = (const float*)d_in[0];
    const float* w1    = (const float*)d_in[1];
    const float* b1    = (const float*)d_in[2];
    const float* g1    = (const float*)d_in[3];
    const float* be1   = (const float*)d_in[4];
    const float* m1    = (const float*)d_in[5];
    const float* v1    = (const float*)d_in[6];
    const float* w_off = (const float*)d_in[7];
    const float* b_off = (const float*)d_in[8];
    const float* w_mod = (const float*)d_in[9];
    const float* b_mod = (const float*)d_in[10];
    const float* w_def = (const float*)d_in[11];
    const float* b_def = (const float*)d_in[12];
    const float* g2    = (const float*)d_in[13];
    const float* be2   = (const float*)d_in[14];
    const float* m2    = (const float*)d_in[15];
    const float* v2    = (const float*)d_in[16];
    const float* w_ds  = (const float*)d_in[17];
    const float* b_ds  = (const float*)d_in[18];
    const float* g3    = (const float*)d_in[19];
    const float* be3   = (const float*)d_in[20];
    const float* m3    = (const float*)d_in[21];
    const float* v3    = (const float*)d_in[22];

    const int C1 = 147456, C2 = 36864, C3 = 163840;
    char* wsp = (char*)d_ws;
    auto alloc = [&](size_t bytes) { char* r = wsp; wsp += (bytes + 255) & ~(size_t)255; return r; };
    const size_t szX0 = (size_t)NN * 66 * 66 * 128 * 2;
    const size_t szX1 = (size_t)NN * 67 * 67 * 128 * 2;
    u16*   Xpad0  = (u16*)alloc(szX0);
    u16*   Xpad1  = (u16*)alloc(szX1);
    u16*   Hpad   = (u16*)alloc(szX1);
    float* OFFMSK = (float*)alloc((size_t)(16900 + 64) * 32 * 4);
    float* T      = (float*)alloc((size_t)16900 * 128 * 4);
    u16*   Wb1p   = (u16*)alloc((size_t)2 * C1 * 2);
    u16*   Wbomp  = (u16*)alloc((size_t)2 * C2 * 2);
    u16*   Wbdp   = (u16*)alloc((size_t)2 * C3 * 2);
    float* bias1f = (float*)alloc(2 * 128 * 4);
    float* biasOM = (float*)alloc(2 * 32 * 4);
    float* biasC  = (float*)alloc(2 * 128 * 4);

    // ---- prologue: layout conversion + weight packing (both instances) ----
    hipMemsetAsync((void*)Xpad0, 0, szX0, stream);
    hipMemsetAsync((void*)Xpad1, 0, szX1, stream);
    x0_to_nhwc<<<(NN * 64 * 64 * 16 + 255) / 256, 256, 0, stream>>>(x0, Xpad0);
    int ptot = 2 * C1 + 2 * C2 + 2 * C3 + 2 * 288;
    wprep_k<<<(ptot + 255) / 256, 256, 0, stream>>>(
        w1, b1, g1, be1, m1, v1, w_off, b_off, w_mod, b_mod, w_def, b_def,
        g2, be2, m2, v2, w_ds, b_ds, g3, be3, m3, v3,
        Wb1p, Wbomp, Wbdp, bias1f, biasOM, biasC);

    const u16* curX = Xpad0;
    for (int i = 0; i < 2; ++i) {
        int H = 64 + i, W = 64 + i;
        int HW = H * W;
        int npb = (HW + 63) / 64;
        int grid = NN * npb;

        hipMemsetAsync((void*)Hpad, 0, szX1, stream);
        // h = relu(bn1(conv3x3(x)))
        gconv_h<2, 4, 2, 2, 8, 0><<<grid, 512, 0, stream>>>(
            curX, Wb1p + (size_t)i * C1, bias1f + i * 128, Hpad, H, W, npb);
        // off(18) + msk(9, 2*sigmoid) -> OFFMSK [pix][32]
        gconv_h<4, 2, 1, 1, 2, 1><<<grid, 512, 0, stream>>>(
            Hpad, Wbomp + (size_t)i * C2, biasOM + i * 32, OFFMSK, H, W, npb);
        // fused deformable conv + residual + bn2/bn3 + relu
        deform_h<<<grid, 512, 0, stream>>>(
            Hpad, curX, OFFMSK, Wbdp + (size_t)i * C3, biasC + i * 128, T, H, W, npb);
        // maxpool
        if (i == 0) {
            pool_k<0><<<(NN * 65 * 65 * 16 + 255) / 256, 256, 0, stream>>>(T, Xpad1, H, W);
        } else {
            pool_k<1><<<(NN * 66 * 66 * 16 + 255) / 256, 256, 0, stream>>>(T, d_out, H, W);
        }
        curX = Xpad1;
    }
}